// Round 1
// baseline (1622.952 us; speedup 1.0000x reference)
//
#include <hip/hip_runtime.h>
#include <math.h>

// GATv2 x3 + log_softmax for MI355X (gfx950).
// Round 1: correctness-first fp32 baseline.
//   per layer: GEMM(gl,gr) -> edge score+atomicMax -> exp+atomicAdd denom -> atomic scatter
// All accumulators zeroed via hipMemsetAsync (d_ws is poisoned each call).

#define TPB 256

__device__ __forceinline__ unsigned fmap(float f) {
  unsigned u = __float_as_uint(f);
  return (u & 0x80000000u) ? ~u : (u | 0x80000000u);
}
__device__ __forceinline__ float funmap(unsigned u) {
  return __uint_as_float((u & 0x80000000u) ? (u ^ 0x80000000u) : ~u);
}
__device__ __forceinline__ void atomAddF(float* p, float v) {
  __hip_atomic_fetch_add(p, v, __ATOMIC_RELAXED, __HIP_MEMORY_SCOPE_AGENT);
}

// ---------------- GEMM: gl = act(x) @ Wl, gr = act(x) @ Wr ----------------
// ACT: 0 none, 1 ELU, 2 ReLU (applied to the INPUT read, i.e. prev layer's act)
template <int K, int M, int NB, int ACT>
__global__ void k_gemm(const float* __restrict__ x, const float* __restrict__ Wl,
                       const float* __restrict__ Wr, float* __restrict__ gl,
                       float* __restrict__ gr, int n) {
  __shared__ float xs[NB][K];
  int base = blockIdx.x * NB;
  for (int i = threadIdx.x; i < NB * K; i += blockDim.x) {
    int r = i / K, k = i - r * K;
    int node = base + r;
    float v = (node < n) ? x[(size_t)node * K + k] : 0.f;
    if (ACT == 1) v = v > 0.f ? v : (__expf(v) - 1.f);
    else if (ACT == 2) v = fmaxf(v, 0.f);
    xs[r][k] = v;
  }
  __syncthreads();
  for (int m = threadIdx.x; m < M; m += blockDim.x) {
    float accl[NB], accr[NB];
#pragma unroll
    for (int r = 0; r < NB; ++r) { accl[r] = 0.f; accr[r] = 0.f; }
    for (int k = 0; k < K; ++k) {
      float wl = Wl[(size_t)k * M + m];
      float wr = Wr[(size_t)k * M + m];
#pragma unroll
      for (int r = 0; r < NB; ++r) {
        accl[r] = fmaf(xs[r][k], wl, accl[r]);
        accr[r] = fmaf(xs[r][k], wr, accr[r]);
      }
    }
#pragma unroll
    for (int r = 0; r < NB; ++r) {
      int node = base + r;
      if (node < n) {
        gl[(size_t)node * M + m] = accl[r];
        gr[(size_t)node * M + m] = accr[r];
      }
    }
  }
}

// ---------------- edge score + running segment max ----------------
template <int H, int F>
__global__ void k_score(const float* __restrict__ gl, const float* __restrict__ gr,
                        const float* __restrict__ att, const int* __restrict__ src,
                        const int* __restrict__ dst, float* __restrict__ score,
                        unsigned* __restrict__ mbuf, int E) {
  int gid = blockIdx.x * blockDim.x + threadIdx.x;  // e*H + h
  if (gid >= E * H) return;
  int e = gid / H, h = gid - e * H;
  int s = src[e], d = dst[e];
  const float4* pg = reinterpret_cast<const float4*>(gl + ((size_t)s * H + h) * F);
  const float4* pr = reinterpret_cast<const float4*>(gr + ((size_t)d * H + h) * F);
  const float4* pa = reinterpret_cast<const float4*>(att + h * F);
  float acc = 0.f;
#pragma unroll
  for (int i = 0; i < F / 4; ++i) {
    float4 a = pg[i], b = pr[i], w = pa[i];
    float v;
    v = a.x + b.x; v = v > 0.f ? v : 0.2f * v; acc = fmaf(v, w.x, acc);
    v = a.y + b.y; v = v > 0.f ? v : 0.2f * v; acc = fmaf(v, w.y, acc);
    v = a.z + b.z; v = v > 0.f ? v : 0.2f * v; acc = fmaf(v, w.z, acc);
    v = a.w + b.w; v = v > 0.f ? v : 0.2f * v; acc = fmaf(v, w.w, acc);
  }
  score[gid] = acc;
  atomicMax(mbuf + (size_t)d * H + h, fmap(acc));
}

// ---------------- exp(score - m[dst]) + segment sum ----------------
template <int H>
__global__ void k_exp(float* __restrict__ score, const unsigned* __restrict__ mbuf,
                      const int* __restrict__ dst, float* __restrict__ denom, int E) {
  int gid = blockIdx.x * blockDim.x + threadIdx.x;
  if (gid >= E * H) return;
  int e = gid / H, h = gid - e * H;
  int d = dst[e];
  float mv = funmap(mbuf[(size_t)d * H + h]);
  float a = __expf(score[gid] - mv);
  score[gid] = a;
  atomAddF(denom + (size_t)d * H + h, a);
}

// ---------------- out[dst] += (a/denom) * gl[src] ----------------
template <int H, int F>
__global__ void k_scatter(const float* __restrict__ gl, const float* __restrict__ score,
                          const float* __restrict__ denom, const int* __restrict__ src,
                          const int* __restrict__ dst, float* __restrict__ out, int E) {
  int gid = blockIdx.x * blockDim.x + threadIdx.x;  // (e*H + h)*F + f
  int tot = E * H * F;  // <= 102.4M, fits int
  if (gid >= tot) return;
  int f = gid % F;
  int eh = gid / F;
  int e = eh / H, h = eh - e * H;
  int s = src[e], d = dst[e];
  float w = score[eh] / (denom[(size_t)d * H + h] + 1e-16f);
  atomAddF(out + ((size_t)d * H + h) * F + f, w * gl[((size_t)s * H + h) * F + f]);
}

// ---------------- row-wise log_softmax over C=40 ----------------
__global__ void k_logsoftmax(const float* __restrict__ in, float* __restrict__ out,
                             int n, int C) {
  int node = blockIdx.x;
  int t = threadIdx.x;  // 64 lanes
  float v = (t < C) ? in[(size_t)node * C + t] : -INFINITY;
  float mx = v;
#pragma unroll
  for (int o = 32; o > 0; o >>= 1) mx = fmaxf(mx, __shfl_xor(mx, o));
  float ex = (t < C) ? __expf(v - mx) : 0.f;
  float sm = ex;
#pragma unroll
  for (int o = 32; o > 0; o >>= 1) sm += __shfl_xor(sm, o);
  if (t < C) out[(size_t)node * C + t] = v - mx - logf(sm);
}

static inline int cdiv(long long a, int b) { return (int)((a + b - 1) / b); }

extern "C" void kernel_launch(void* const* d_in, const int* in_sizes, int n_in,
                              void* d_out, int out_size, void* d_ws, size_t ws_size,
                              hipStream_t stream) {
  const float* x    = (const float*)d_in[0];
  const float* Wl1  = (const float*)d_in[1];
  const float* Wr1  = (const float*)d_in[2];
  const float* att1 = (const float*)d_in[3];
  const float* Wl2  = (const float*)d_in[4];
  const float* Wr2  = (const float*)d_in[5];
  const float* att2 = (const float*)d_in[6];
  const float* Wl3  = (const float*)d_in[7];
  const float* Wr3  = (const float*)d_in[8];
  const float* att3 = (const float*)d_in[9];
  const int*   ei   = (const int*)d_in[10];

  const int N = in_sizes[0] / 128;   // 50000
  const int E = in_sizes[10] / 2;    // 800000
  const int* src = ei;
  const int* dst = ei + E;

  // workspace layout (floats)
  float* ws    = (float*)d_ws;
  float* bufA  = ws;                            // N*128  (layer in/out, reused)
  float* bufGL = bufA + (size_t)N * 128;        // N*128
  float* bufGR = bufGL + (size_t)N * 128;       // N*128
  float* score = bufGR + (size_t)N * 128;       // E*4
  float* denom = score + (size_t)E * 4;         // N*4
  unsigned* mbuf = (unsigned*)(denom + (size_t)N * 4);  // N*4
  float* out3  = score + E;                     // layer3 out (N*40) in score tail

  float* outf = (float*)d_out;

  // ---------------- layer 1 (input x, no input act) ----------------
  k_gemm<128, 128, 8, 0><<<cdiv(N, 8), 128, 0, stream>>>(x, Wl1, Wr1, bufGL, bufGR, N);
  hipMemsetAsync(denom, 0, (size_t)N * 4 * sizeof(float) * 2, stream);  // denom + mbuf
  hipMemsetAsync(bufA, 0, (size_t)N * 128 * sizeof(float), stream);
  k_score<4, 32><<<cdiv((long long)E * 4, TPB), TPB, 0, stream>>>(bufGL, bufGR, att1, src, dst, score, mbuf, E);
  k_exp<4><<<cdiv((long long)E * 4, TPB), TPB, 0, stream>>>(score, mbuf, dst, denom, E);
  k_scatter<4, 32><<<cdiv((long long)E * 128, TPB), TPB, 0, stream>>>(bufGL, score, denom, src, dst, bufA, E);

  // ---------------- layer 2 (input bufA with ELU) ----------------
  k_gemm<128, 128, 8, 1><<<cdiv(N, 8), 128, 0, stream>>>(bufA, Wl2, Wr2, bufGL, bufGR, N);
  hipMemsetAsync(denom, 0, (size_t)N * 4 * sizeof(float) * 2, stream);
  hipMemsetAsync(bufA, 0, (size_t)N * 128 * sizeof(float), stream);
  k_score<4, 32><<<cdiv((long long)E * 4, TPB), TPB, 0, stream>>>(bufGL, bufGR, att2, src, dst, score, mbuf, E);
  k_exp<4><<<cdiv((long long)E * 4, TPB), TPB, 0, stream>>>(score, mbuf, dst, denom, E);
  k_scatter<4, 32><<<cdiv((long long)E * 128, TPB), TPB, 0, stream>>>(bufGL, score, denom, src, dst, bufA, E);

  // ---------------- layer 3 (input bufA with ReLU, H=1, F=40) ----------------
  k_gemm<128, 40, 8, 2><<<cdiv(N, 8), 128, 0, stream>>>(bufA, Wl3, Wr3, bufGL, bufGR, N);
  hipMemsetAsync(denom, 0, (size_t)N * 1 * sizeof(float), stream);
  hipMemsetAsync(mbuf, 0, (size_t)N * 1 * sizeof(unsigned), stream);
  hipMemsetAsync(out3, 0, (size_t)N * 40 * sizeof(float), stream);
  k_score<1, 40><<<cdiv(E, TPB), TPB, 0, stream>>>(bufGL, bufGR, att3, src, dst, score, mbuf, E);
  k_exp<1><<<cdiv(E, TPB), TPB, 0, stream>>>(score, mbuf, dst, denom, E);
  k_scatter<1, 40><<<cdiv((long long)E * 40, TPB), TPB, 0, stream>>>(bufGL, score, denom, src, dst, out3, E);

  // ---------------- log_softmax ----------------
  k_logsoftmax<<<N, 64, 0, stream>>>(out3, outf, N, 40);
}

// Round 2
// 713.129 us; speedup vs baseline: 2.2758x; 2.2758x over previous
//
#include <hip/hip_runtime.h>
#include <math.h>

// GATv2 x3 + log_softmax for MI355X (gfx950).
// Round 2: CSR-by-dst + fused per-dst online-softmax aggregation (no f32 atomics).
//   once: histogram(dst) -> scan -> fill csr_src
//   per layer: GEMM(gl,gr) -> wave-per-dst fused score/softmax/aggregate
// d_ws is re-poisoned 0xAA before every call; cnt is the only buffer we memset.

#define TPB 256

// ---------------- GEMM: gl = act(x) @ Wl, gr = act(x) @ Wr ----------------
// ACT: 0 none, 1 ELU, 2 ReLU (applied to the INPUT read, i.e. prev layer's act)
template <int K, int M, int NB, int ACT>
__global__ void k_gemm(const float* __restrict__ x, const float* __restrict__ Wl,
                       const float* __restrict__ Wr, float* __restrict__ gl,
                       float* __restrict__ gr, int n) {
  __shared__ float xs[NB][K];
  int base = blockIdx.x * NB;
  for (int i = threadIdx.x; i < NB * K; i += blockDim.x) {
    int r = i / K, k = i - r * K;
    int node = base + r;
    float v = (node < n) ? x[(size_t)node * K + k] : 0.f;
    if (ACT == 1) v = v > 0.f ? v : (__expf(v) - 1.f);
    else if (ACT == 2) v = fmaxf(v, 0.f);
    xs[r][k] = v;
  }
  __syncthreads();
  for (int m = threadIdx.x; m < M; m += blockDim.x) {
    float accl[NB], accr[NB];
#pragma unroll
    for (int r = 0; r < NB; ++r) { accl[r] = 0.f; accr[r] = 0.f; }
    for (int k = 0; k < K; ++k) {
      float wl = Wl[(size_t)k * M + m];
      float wr = Wr[(size_t)k * M + m];
#pragma unroll
      for (int r = 0; r < NB; ++r) {
        accl[r] = fmaf(xs[r][k], wl, accl[r]);
        accr[r] = fmaf(xs[r][k], wr, accr[r]);
      }
    }
#pragma unroll
    for (int r = 0; r < NB; ++r) {
      int node = base + r;
      if (node < n) {
        gl[(size_t)node * M + m] = accl[r];
        gr[(size_t)node * M + m] = accr[r];
      }
    }
  }
}

// ---------------- CSR build ----------------
__global__ void k_hist(const int* __restrict__ dst, int* __restrict__ cnt, int E) {
  int e = blockIdx.x * blockDim.x + threadIdx.x;
  if (e < E) atomicAdd(&cnt[dst[e]], 1);
}

// single-block chunked exclusive scan: rowptr[0..n] from cnt[0..n)
__global__ void k_scan(const int* __restrict__ cnt, int* __restrict__ rowptr, int n) {
  const int T = 1024;
  __shared__ int wsum[16];
  __shared__ int carry_s;
  int lane = threadIdx.x & 63, wid = threadIdx.x >> 6;
  if (threadIdx.x == 0) carry_s = 0;
  __syncthreads();
  for (int base = 0; base < n; base += T) {
    int i = base + threadIdx.x;
    int v = (i < n) ? cnt[i] : 0;
    int x = v;
#pragma unroll
    for (int off = 1; off < 64; off <<= 1) {
      int t = __shfl_up(x, off);
      if (lane >= off) x += t;
    }
    if (lane == 63) wsum[wid] = x;
    __syncthreads();
    if (wid == 0) {
      int w = (lane < 16) ? wsum[lane] : 0;
#pragma unroll
      for (int off = 1; off < 16; off <<= 1) {
        int t = __shfl_up(w, off);
        if (lane >= off) w += t;
      }
      if (lane < 16) wsum[lane] = w;  // inclusive wave-sums scan
    }
    __syncthreads();
    int woff = (wid > 0) ? wsum[wid - 1] : 0;
    if (i < n) rowptr[i] = carry_s + woff + x - v;  // exclusive
    __syncthreads();
    if (threadIdx.x == T - 1) carry_s += wsum[15];
    __syncthreads();
  }
  if (threadIdx.x == 0) rowptr[n] = carry_s;
}

__global__ void k_fill(const int* __restrict__ src, const int* __restrict__ dst,
                       int* __restrict__ cur, int* __restrict__ csr_src, int E) {
  int e = blockIdx.x * blockDim.x + threadIdx.x;
  if (e >= E) return;
  int pos = atomicAdd(&cur[dst[e]], 1);
  csr_src[pos] = src[e];
}

// ---------------- fused per-dst edge kernel, H=4 F=32 (HF=128) ----------------
// one wave per dst; lane holds features [2*lane, 2*lane+1]; head = lane/16
__global__ void k_edge4(const float* __restrict__ gl, const float* __restrict__ gr,
                        const float* __restrict__ att, const int* __restrict__ rowptr,
                        const int* __restrict__ csr_src, float* __restrict__ out, int n) {
  int wid = (int)((blockIdx.x * blockDim.x + threadIdx.x) >> 6);
  if (wid >= n) return;
  int lane = threadIdx.x & 63;
  const float2 grv = reinterpret_cast<const float2*>(gr + (size_t)wid * 128)[lane];
  const float2 attv = reinterpret_cast<const float2*>(att)[lane];
  int p0 = rowptr[wid], p1 = rowptr[wid + 1];
  float m = -INFINITY, l = 0.f;
  float2 acc = {0.f, 0.f};
  for (int p = p0; p < p1; ++p) {
    int s = csr_src[p];
    float2 g = reinterpret_cast<const float2*>(gl + (size_t)s * 128)[lane];
    float vx = g.x + grv.x; vx = vx > 0.f ? vx : 0.2f * vx;
    float vy = g.y + grv.y; vy = vy > 0.f ? vy : 0.2f * vy;
    float part = fmaf(vx, attv.x, vy * attv.y);
    part += __shfl_xor(part, 1);
    part += __shfl_xor(part, 2);
    part += __shfl_xor(part, 4);
    part += __shfl_xor(part, 8);   // 16-lane head group -> per-head score
    float mn = fmaxf(m, part);
    float scale = __expf(m - mn);   // m=-inf on first edge -> 0
    float w = __expf(part - mn);
    l = l * scale + w;
    acc.x = fmaf(acc.x, scale, w * g.x);
    acc.y = fmaf(acc.y, scale, w * g.y);
    m = mn;
  }
  float inv = (p1 > p0) ? 1.f / (l + 1e-16f) : 0.f;
  float2 o = {acc.x * inv, acc.y * inv};
  reinterpret_cast<float2*>(out + (size_t)wid * 128)[lane] = o;
}

// ---------------- fused per-dst edge kernel, H=1 F=40 ----------------
__global__ void k_edge1(const float* __restrict__ gl, const float* __restrict__ gr,
                        const float* __restrict__ att, const int* __restrict__ rowptr,
                        const int* __restrict__ csr_src, float* __restrict__ out, int n) {
  int wid = (int)((blockIdx.x * blockDim.x + threadIdx.x) >> 6);
  if (wid >= n) return;
  int lane = threadIdx.x & 63;
  bool act = lane < 40;
  float grv = act ? gr[(size_t)wid * 40 + lane] : 0.f;
  float attv = act ? att[lane] : 0.f;
  int p0 = rowptr[wid], p1 = rowptr[wid + 1];
  float m = -INFINITY, l = 0.f, acc = 0.f;
  for (int p = p0; p < p1; ++p) {
    int s = csr_src[p];
    float g = act ? gl[(size_t)s * 40 + lane] : 0.f;
    float v = g + grv; v = v > 0.f ? v : 0.2f * v;
    float part = v * attv;
#pragma unroll
    for (int off = 1; off < 64; off <<= 1) part += __shfl_xor(part, off);
    float mn = fmaxf(m, part);
    float scale = __expf(m - mn);
    float w = __expf(part - mn);
    l = l * scale + w;
    acc = fmaf(acc, scale, w * g);
    m = mn;
  }
  float inv = (p1 > p0) ? 1.f / (l + 1e-16f) : 0.f;
  if (act) out[(size_t)wid * 40 + lane] = acc * inv;
}

// ---------------- row-wise log_softmax over C=40 ----------------
__global__ void k_logsoftmax(const float* __restrict__ in, float* __restrict__ out,
                             int n, int C) {
  int node = blockIdx.x;
  int t = threadIdx.x;  // 64 lanes
  float v = (t < C) ? in[(size_t)node * C + t] : -INFINITY;
  float mx = v;
#pragma unroll
  for (int o = 32; o > 0; o >>= 1) mx = fmaxf(mx, __shfl_xor(mx, o));
  float ex = (t < C) ? __expf(v - mx) : 0.f;
  float sm = ex;
#pragma unroll
  for (int o = 32; o > 0; o >>= 1) sm += __shfl_xor(sm, o);
  if (t < C) out[(size_t)node * C + t] = v - mx - logf(sm);
}

static inline int cdiv(long long a, int b) { return (int)((a + b - 1) / b); }

extern "C" void kernel_launch(void* const* d_in, const int* in_sizes, int n_in,
                              void* d_out, int out_size, void* d_ws, size_t ws_size,
                              hipStream_t stream) {
  const float* x    = (const float*)d_in[0];
  const float* Wl1  = (const float*)d_in[1];
  const float* Wr1  = (const float*)d_in[2];
  const float* att1 = (const float*)d_in[3];
  const float* Wl2  = (const float*)d_in[4];
  const float* Wr2  = (const float*)d_in[5];
  const float* att2 = (const float*)d_in[6];
  const float* Wl3  = (const float*)d_in[7];
  const float* Wr3  = (const float*)d_in[8];
  const float* att3 = (const float*)d_in[9];
  const int*   ei   = (const int*)d_in[10];

  const int N = in_sizes[0] / 128;   // 50000
  const int E = in_sizes[10] / 2;    // 800000
  const int* src = ei;
  const int* dst = ei + E;

  // workspace layout
  float* ws     = (float*)d_ws;
  float* bufA   = ws;                             // N*128
  float* bufGL  = bufA + (size_t)N * 128;         // N*128
  float* bufGR  = bufGL + (size_t)N * 128;        // N*128
  float* out3   = bufGR + (size_t)N * 128;        // N*40
  int*   cnt    = (int*)(out3 + (size_t)N * 40);  // N
  int*   rowptr = cnt + N;                        // N+1
  int*   cur    = rowptr + N + 1;                 // N
  int*   csrS   = cur + N;                        // E

  float* outf = (float*)d_out;

  // ---------------- CSR build (once, reused by all 3 layers) ----------------
  hipMemsetAsync(cnt, 0, (size_t)N * sizeof(int), stream);
  k_hist<<<cdiv(E, TPB), TPB, 0, stream>>>(dst, cnt, E);
  k_scan<<<1, 1024, 0, stream>>>(cnt, rowptr, N);
  hipMemcpyAsync(cur, rowptr, (size_t)N * sizeof(int), hipMemcpyDeviceToDevice, stream);
  k_fill<<<cdiv(E, TPB), TPB, 0, stream>>>(src, dst, cur, csrS, E);

  // ---------------- layer 1 (input x, no input act) ----------------
  k_gemm<128, 128, 8, 0><<<cdiv(N, 8), 128, 0, stream>>>(x, Wl1, Wr1, bufGL, bufGR, N);
  k_edge4<<<cdiv(N, 4), TPB, 0, stream>>>(bufGL, bufGR, att1, rowptr, csrS, bufA, N);

  // ---------------- layer 2 (input bufA with ELU) ----------------
  k_gemm<128, 128, 8, 1><<<cdiv(N, 8), 128, 0, stream>>>(bufA, Wl2, Wr2, bufGL, bufGR, N);
  k_edge4<<<cdiv(N, 4), TPB, 0, stream>>>(bufGL, bufGR, att2, rowptr, csrS, bufA, N);

  // ---------------- layer 3 (input bufA with ReLU, H=1, F=40) ----------------
  k_gemm<128, 40, 8, 2><<<cdiv(N, 8), 128, 0, stream>>>(bufA, Wl3, Wr3, bufGL, bufGR, N);
  k_edge1<<<cdiv(N, 4), TPB, 0, stream>>>(bufGL, bufGR, att3, rowptr, csrS, out3, N);

  // ---------------- log_softmax ----------------
  k_logsoftmax<<<N, 64, 0, stream>>>(out3, outf, N, 40);
}

// Round 3
// 614.557 us; speedup vs baseline: 2.6408x; 1.1604x over previous
//
#include <hip/hip_runtime.h>
#include <math.h>

// GATv2 x3 + log_softmax for MI355X (gfx950).
// Round 3: latency attack on fused edge kernels.
//   - csr_src chunk-broadcast via __shfl (index load off the critical path)
//   - 4 (resp 2) independent online-softmax chains -> 4 gathers in flight
//   - GEMM NB=16 (halve W re-reads)

#define TPB 256

// ---------------- GEMM: gl = act(x) @ Wl, gr = act(x) @ Wr ----------------
// ACT: 0 none, 1 ELU, 2 ReLU (applied to the INPUT read, i.e. prev layer's act)
template <int K, int M, int NB, int ACT>
__global__ void k_gemm(const float* __restrict__ x, const float* __restrict__ Wl,
                       const float* __restrict__ Wr, float* __restrict__ gl,
                       float* __restrict__ gr, int n) {
  __shared__ float xs[NB][K];
  int base = blockIdx.x * NB;
  for (int i = threadIdx.x; i < NB * K; i += blockDim.x) {
    int r = i / K, k = i - r * K;
    int node = base + r;
    float v = (node < n) ? x[(size_t)node * K + k] : 0.f;
    if (ACT == 1) v = v > 0.f ? v : (__expf(v) - 1.f);
    else if (ACT == 2) v = fmaxf(v, 0.f);
    xs[r][k] = v;
  }
  __syncthreads();
  for (int m = threadIdx.x; m < M; m += blockDim.x) {
    float accl[NB], accr[NB];
#pragma unroll
    for (int r = 0; r < NB; ++r) { accl[r] = 0.f; accr[r] = 0.f; }
    for (int k = 0; k < K; ++k) {
      float wl = Wl[(size_t)k * M + m];
      float wr = Wr[(size_t)k * M + m];
#pragma unroll
      for (int r = 0; r < NB; ++r) {
        accl[r] = fmaf(xs[r][k], wl, accl[r]);
        accr[r] = fmaf(xs[r][k], wr, accr[r]);
      }
    }
#pragma unroll
    for (int r = 0; r < NB; ++r) {
      int node = base + r;
      if (node < n) {
        gl[(size_t)node * M + m] = accl[r];
        gr[(size_t)node * M + m] = accr[r];
      }
    }
  }
}

// ---------------- CSR build ----------------
__global__ void k_hist(const int* __restrict__ dst, int* __restrict__ cnt, int E) {
  int e = blockIdx.x * blockDim.x + threadIdx.x;
  if (e < E) atomicAdd(&cnt[dst[e]], 1);
}

// single-block chunked exclusive scan: rowptr[0..n] from cnt[0..n)
__global__ void k_scan(const int* __restrict__ cnt, int* __restrict__ rowptr, int n) {
  const int T = 1024;
  __shared__ int wsum[16];
  __shared__ int carry_s;
  int lane = threadIdx.x & 63, wid = threadIdx.x >> 6;
  if (threadIdx.x == 0) carry_s = 0;
  __syncthreads();
  for (int base = 0; base < n; base += T) {
    int i = base + threadIdx.x;
    int v = (i < n) ? cnt[i] : 0;
    int x = v;
#pragma unroll
    for (int off = 1; off < 64; off <<= 1) {
      int t = __shfl_up(x, off);
      if (lane >= off) x += t;
    }
    if (lane == 63) wsum[wid] = x;
    __syncthreads();
    if (wid == 0) {
      int w = (lane < 16) ? wsum[lane] : 0;
#pragma unroll
      for (int off = 1; off < 16; off <<= 1) {
        int t = __shfl_up(w, off);
        if (lane >= off) w += t;
      }
      if (lane < 16) wsum[lane] = w;  // inclusive wave-sums scan
    }
    __syncthreads();
    int woff = (wid > 0) ? wsum[wid - 1] : 0;
    if (i < n) rowptr[i] = carry_s + woff + x - v;  // exclusive
    __syncthreads();
    if (threadIdx.x == T - 1) carry_s += wsum[15];
    __syncthreads();
  }
  if (threadIdx.x == 0) rowptr[n] = carry_s;
}

__global__ void k_fill(const int* __restrict__ src, const int* __restrict__ dst,
                       int* __restrict__ cur, int* __restrict__ csr_src, int E) {
  int e = blockIdx.x * blockDim.x + threadIdx.x;
  if (e >= E) return;
  int pos = atomicAdd(&cur[dst[e]], 1);
  csr_src[pos] = src[e];
}

// ---------------- fused per-dst edge kernel, H=4 F=32 (HF=128) ----------------
// one wave per dst; lane holds features [2*lane, 2*lane+1]; head = lane/16
// 4 independent online-softmax chains + csr chunk broadcast.
__global__ void k_edge4(const float* __restrict__ gl, const float* __restrict__ gr,
                        const float* __restrict__ att, const int* __restrict__ rowptr,
                        const int* __restrict__ csr_src, float* __restrict__ out, int n) {
  int wid = (int)((blockIdx.x * blockDim.x + threadIdx.x) >> 6);
  if (wid >= n) return;
  int lane = threadIdx.x & 63;
  int p0 = rowptr[wid], p1 = rowptr[wid + 1];
  float2* po = reinterpret_cast<float2*>(out + (size_t)wid * 128);
  if (p1 <= p0) { po[lane] = make_float2(0.f, 0.f); return; }
  const float2 grv = reinterpret_cast<const float2*>(gr + (size_t)wid * 128)[lane];
  const float2 attv = reinterpret_cast<const float2*>(att)[lane];

  float m[4], l[4];
  float2 acc[4];
#pragma unroll
  for (int j = 0; j < 4; ++j) { m[j] = -INFINITY; l[j] = 0.f; acc[j] = make_float2(0.f, 0.f); }

#define UPD4(J, G)                                                     \
  {                                                                    \
    float vx = (G).x + grv.x; vx = vx > 0.f ? vx : 0.2f * vx;          \
    float vy = (G).y + grv.y; vy = vy > 0.f ? vy : 0.2f * vy;          \
    float part = fmaf(vx, attv.x, vy * attv.y);                        \
    part += __shfl_xor(part, 1);                                       \
    part += __shfl_xor(part, 2);                                       \
    part += __shfl_xor(part, 4);                                       \
    part += __shfl_xor(part, 8);                                       \
    float mn = fmaxf(m[J], part);                                      \
    float sc = __expf(m[J] - mn);                                      \
    float w = __expf(part - mn);                                       \
    l[J] = l[J] * sc + w;                                              \
    acc[J].x = fmaf(acc[J].x, sc, w * (G).x);                          \
    acc[J].y = fmaf(acc[J].y, sc, w * (G).y);                          \
    m[J] = mn;                                                         \
  }

  for (int base = p0; base < p1; base += 64) {
    int nv = p1 - base; if (nv > 64) nv = 64;
    int sv = (base + lane < p1) ? csr_src[base + lane] : 0;
    int i = 0;
    for (; i + 4 <= nv; i += 4) {
      int s0 = __shfl(sv, i + 0);
      int s1 = __shfl(sv, i + 1);
      int s2 = __shfl(sv, i + 2);
      int s3 = __shfl(sv, i + 3);
      float2 g0 = reinterpret_cast<const float2*>(gl + ((size_t)s0 << 7))[lane];
      float2 g1 = reinterpret_cast<const float2*>(gl + ((size_t)s1 << 7))[lane];
      float2 g2 = reinterpret_cast<const float2*>(gl + ((size_t)s2 << 7))[lane];
      float2 g3 = reinterpret_cast<const float2*>(gl + ((size_t)s3 << 7))[lane];
      UPD4(0, g0);
      UPD4(1, g1);
      UPD4(2, g2);
      UPD4(3, g3);
    }
    for (; i < nv; ++i) {
      int s0 = __shfl(sv, i);
      float2 g0 = reinterpret_cast<const float2*>(gl + ((size_t)s0 << 7))[lane];
      UPD4(0, g0);
    }
  }
#undef UPD4

  // merge the 4 chains (chain 0 is guaranteed non-empty; empty chains give exp(-inf)=0)
  float mn = fmaxf(fmaxf(m[0], m[1]), fmaxf(m[2], m[3]));
  float lt = 0.f;
  float2 at = make_float2(0.f, 0.f);
#pragma unroll
  for (int j = 0; j < 4; ++j) {
    float sc = __expf(m[j] - mn);
    lt = fmaf(l[j], sc, lt);
    at.x = fmaf(acc[j].x, sc, at.x);
    at.y = fmaf(acc[j].y, sc, at.y);
  }
  float inv = 1.f / (lt + 1e-16f);
  po[lane] = make_float2(at.x * inv, at.y * inv);
}

// ---------------- fused per-dst edge kernel, H=1 F=40 ----------------
__global__ void k_edge1(const float* __restrict__ gl, const float* __restrict__ gr,
                        const float* __restrict__ att, const int* __restrict__ rowptr,
                        const int* __restrict__ csr_src, float* __restrict__ out, int n) {
  int wid = (int)((blockIdx.x * blockDim.x + threadIdx.x) >> 6);
  if (wid >= n) return;
  int lane = threadIdx.x & 63;
  bool actl = lane < 40;
  int p0 = rowptr[wid], p1 = rowptr[wid + 1];
  if (p1 <= p0) { if (actl) out[(size_t)wid * 40 + lane] = 0.f; return; }
  float grv = actl ? gr[(size_t)wid * 40 + lane] : 0.f;
  float attv = actl ? att[lane] : 0.f;

  float m[2], l[2], acc[2];
#pragma unroll
  for (int j = 0; j < 2; ++j) { m[j] = -INFINITY; l[j] = 0.f; acc[j] = 0.f; }

#define UPD1(J, G)                                                     \
  {                                                                    \
    float v = (G) + grv; v = v > 0.f ? v : 0.2f * v;                   \
    float part = v * attv;                                             \
    part += __shfl_xor(part, 1);                                       \
    part += __shfl_xor(part, 2);                                       \
    part += __shfl_xor(part, 4);                                       \
    part += __shfl_xor(part, 8);                                       \
    part += __shfl_xor(part, 16);                                      \
    part += __shfl_xor(part, 32);                                      \
    float mn = fmaxf(m[J], part);                                      \
    float sc = __expf(m[J] - mn);                                      \
    float w = __expf(part - mn);                                       \
    l[J] = l[J] * sc + w;                                              \
    acc[J] = fmaf(acc[J], sc, w * (G));                                \
    m[J] = mn;                                                         \
  }

  for (int base = p0; base < p1; base += 64) {
    int nv = p1 - base; if (nv > 64) nv = 64;
    int sv = (base + lane < p1) ? csr_src[base + lane] : 0;
    int i = 0;
    for (; i + 2 <= nv; i += 2) {
      int s0 = __shfl(sv, i + 0);
      int s1 = __shfl(sv, i + 1);
      float g0 = actl ? gl[(size_t)s0 * 40 + lane] : 0.f;
      float g1 = actl ? gl[(size_t)s1 * 40 + lane] : 0.f;
      UPD1(0, g0);
      UPD1(1, g1);
    }
    for (; i < nv; ++i) {
      int s0 = __shfl(sv, i);
      float g0 = actl ? gl[(size_t)s0 * 40 + lane] : 0.f;
      UPD1(0, g0);
    }
  }
#undef UPD1

  float mn = fmaxf(m[0], m[1]);
  float s0 = __expf(m[0] - mn), s1 = __expf(m[1] - mn);
  float lt = l[0] * s0 + l[1] * s1;
  float at = acc[0] * s0 + acc[1] * s1;
  float inv = 1.f / (lt + 1e-16f);
  if (actl) out[(size_t)wid * 40 + lane] = at * inv;
}

// ---------------- row-wise log_softmax over C=40 ----------------
__global__ void k_logsoftmax(const float* __restrict__ in, float* __restrict__ out,
                             int n, int C) {
  int node = blockIdx.x;
  int t = threadIdx.x;  // 64 lanes
  float v = (t < C) ? in[(size_t)node * C + t] : -INFINITY;
  float mx = v;
#pragma unroll
  for (int o = 32; o > 0; o >>= 1) mx = fmaxf(mx, __shfl_xor(mx, o));
  float ex = (t < C) ? __expf(v - mx) : 0.f;
  float sm = ex;
#pragma unroll
  for (int o = 32; o > 0; o >>= 1) sm += __shfl_xor(sm, o);
  if (t < C) out[(size_t)node * C + t] = v - mx - logf(sm);
}

static inline int cdiv(long long a, int b) { return (int)((a + b - 1) / b); }

extern "C" void kernel_launch(void* const* d_in, const int* in_sizes, int n_in,
                              void* d_out, int out_size, void* d_ws, size_t ws_size,
                              hipStream_t stream) {
  const float* x    = (const float*)d_in[0];
  const float* Wl1  = (const float*)d_in[1];
  const float* Wr1  = (const float*)d_in[2];
  const float* att1 = (const float*)d_in[3];
  const float* Wl2  = (const float*)d_in[4];
  const float* Wr2  = (const float*)d_in[5];
  const float* att2 = (const float*)d_in[6];
  const float* Wl3  = (const float*)d_in[7];
  const float* Wr3  = (const float*)d_in[8];
  const float* att3 = (const float*)d_in[9];
  const int*   ei   = (const int*)d_in[10];

  const int N = in_sizes[0] / 128;   // 50000
  const int E = in_sizes[10] / 2;    // 800000
  const int* src = ei;
  const int* dst = ei + E;

  // workspace layout
  float* ws     = (float*)d_ws;
  float* bufA   = ws;                             // N*128
  float* bufGL  = bufA + (size_t)N * 128;         // N*128
  float* bufGR  = bufGL + (size_t)N * 128;        // N*128
  float* out3   = bufGR + (size_t)N * 128;        // N*40
  int*   cnt    = (int*)(out3 + (size_t)N * 40);  // N
  int*   rowptr = cnt + N;                        // N+1
  int*   cur    = rowptr + N + 1;                 // N
  int*   csrS   = cur + N;                        // E

  float* outf = (float*)d_out;

  // ---------------- CSR build (once, reused by all 3 layers) ----------------
  hipMemsetAsync(cnt, 0, (size_t)N * sizeof(int), stream);
  k_hist<<<cdiv(E, TPB), TPB, 0, stream>>>(dst, cnt, E);
  k_scan<<<1, 1024, 0, stream>>>(cnt, rowptr, N);
  hipMemcpyAsync(cur, rowptr, (size_t)N * sizeof(int), hipMemcpyDeviceToDevice, stream);
  k_fill<<<cdiv(E, TPB), TPB, 0, stream>>>(src, dst, cur, csrS, E);

  // ---------------- layer 1 (input x, no input act) ----------------
  k_gemm<128, 128, 16, 0><<<cdiv(N, 16), 128, 0, stream>>>(x, Wl1, Wr1, bufGL, bufGR, N);
  k_edge4<<<cdiv(N, 4), TPB, 0, stream>>>(bufGL, bufGR, att1, rowptr, csrS, bufA, N);

  // ---------------- layer 2 (input bufA with ELU) ----------------
  k_gemm<128, 128, 16, 1><<<cdiv(N, 16), 128, 0, stream>>>(bufA, Wl2, Wr2, bufGL, bufGR, N);
  k_edge4<<<cdiv(N, 4), TPB, 0, stream>>>(bufGL, bufGR, att2, rowptr, csrS, bufA, N);

  // ---------------- layer 3 (input bufA with ReLU, H=1, F=40) ----------------
  k_gemm<128, 40, 16, 2><<<cdiv(N, 16), 128, 0, stream>>>(bufA, Wl3, Wr3, bufGL, bufGR, N);
  k_edge1<<<cdiv(N, 4), TPB, 0, stream>>>(bufGL, bufGR, att3, rowptr, csrS, out3, N);

  // ---------------- log_softmax ----------------
  k_logsoftmax<<<N, 64, 0, stream>>>(out3, outf, N, 40);
}